// Round 9
// baseline (69.687 us; speedup 1.0000x reference)
//
#include <hip/hip_runtime.h>
#include <math.h>

// PolyaTree R9: SINGLE fused kernel. Each block builds the per-dim LUTs
// (127 splits + 128 leaf values, bit-exact node_lohi descent -- validated
// R3..R8, absmax 0.03125) directly into LDS in a ~1.5us prologue, then runs
// the R3 eval core (7 narrow b32 LDS gathers + 1 value gather per point-dim).
// Removes: build_luts launch + graph drain (~10us for tiny kernels) and the
// global->LDS staging round-trip. DS-floor model said R3 core ~19us; R3/R5/R8
// all measured 33-38 regardless of DS count -> overhead was the constant.

constexpr int DIMS     = 16;
constexpr int NODES    = 255;   // 2^8 - 1
constexpr int INTERNAL = 127;
constexpr int LSTRIDE  = 128;

// --- exact-mirror node interval descent (validated R3/R5/R6/R7/R8) ---
__device__ void node_lohi(const float* s, int j, float& lo, float& hi, float& acc) {
#pragma clang fp contract(off)
    unsigned key = (unsigned)(j + 1);   // 1 then path bits (0 = left)
    int level = 31 - __clz(key);
    lo = 0.0f; hi = 1.0f; acc = 0.0f;
    int i = 0;
    for (int tb = level - 1; tb >= 0; --tb) {
        float b = s[i];
        acc += logf(b);
        float len = hi - lo;
        float split = lo + b * len;     // EXACT mirror of reference (no fma)
        unsigned bit = (key >> tb) & 1u;
        if (bit == 0u) { hi = split; }
        else { lo = split; hi = split + (1.0f - b) * len; }
        i = 2 * i + 1 + (int)bit;
    }
}

__global__ __launch_bounds__(256) void polya_fused(
    const float* __restrict__ x,        // (n,16)
    const float* __restrict__ samples,  // (16,255)
    float* __restrict__ out,
    int n)
{
#pragma clang fp contract(off)
    __shared__ float s_split[DIMS * LSTRIDE];   // 8 KB
    __shared__ float s_value[DIMS * LSTRIDE];   // 8 KB

    // ---- prologue: build tables in-block (identical arithmetic to R3) ----
    for (int id = threadIdx.x; id < DIMS * NODES; id += 256) {
        int d = id / NODES;                     // magic-mul, prologue only
        int j = id - d * NODES;
        const float* s = samples + d * NODES;
        float lo, hi, acc;
        node_lohi(s, j, lo, hi, acc);
        float b = s[j];
        if (j < INTERNAL) {
            s_split[d * LSTRIDE + j] = lo + b * (hi - lo);       // exact mirror
        } else {
            s_value[d * LSTRIDE + (j - INTERNAL)] = acc + logf(b) - logf(hi - lo);
        }
    }
    __syncthreads();

    // ---- eval: R3 core, unchanged ----
    const int stride = gridDim.x * 256;
    for (int p = blockIdx.x * 256 + threadIdx.x; p < n; p += stride) {
        const float4* xr = reinterpret_cast<const float4*>(x + (size_t)p * DIMS);
        float4 a = xr[0], b4 = xr[1], c4 = xr[2], e4 = xr[3];
        float xs[DIMS] = {a.x, a.y, a.z, a.w,  b4.x, b4.y, b4.z, b4.w,
                          c4.x, c4.y, c4.z, c4.w,  e4.x, e4.y, e4.z, e4.w};
        float acc = 0.0f;
#pragma unroll
        for (int d = 0; d < DIMS; ++d) {
            const float xv = xs[d];
            int idx = 0;
#pragma unroll
            for (int l = 0; l < 7; ++l) {
                float sp = s_split[d * LSTRIDE + idx];
                idx = 2 * idx + 1 + (int)(xv > sp);   // x<=split -> left
            }
            acc += s_value[d * LSTRIDE + (idx - INTERNAL)];
        }
        out[p] = acc * 0.0625f;   // mean over 16 dims (exact /16)
    }
}

extern "C" void kernel_launch(void* const* d_in, const int* in_sizes, int n_in,
                              void* d_out, int out_size, void* d_ws, size_t ws_size,
                              hipStream_t stream) {
    const float* x       = (const float*)d_in[0];   // (n,16) f32
    const float* samples = (const float*)d_in[1];   // (16,255) f32
    float* out = (float*)d_out;
    const int n = in_sizes[0] / DIMS;

    int blocks = (n + 255) / 256;
    if (blocks > 2048) blocks = 2048;               // ~2 pts/thread grid-stride
    polya_fused<<<blocks, 256, 0, stream>>>(x, samples, out, n);
}

// Round 10
// 32.308 us; speedup vs baseline: 2.1569x; 2.1569x over previous
//
#include <hip/hip_runtime.h>
#include <math.h>

// PolyaTree R10: fused single kernel with CHEAP level-by-level prologue.
// R9's fusion removed ~10us launch overhead but its prologue redid the full
// root-descent per node (~128 logf/thread, VALUBusy 86%, 77us). R10 builds
// the tree incrementally: level l's (lo,hi,acc) from level l-1 via ping-pong
// LDS frontier, ONE logf per parent. Same left-assoc add order and identical
// mul/add exprs (contract off) as the R3-validated node_lohi -> bit-exact.
// Eval core: R3's descent, unchanged (absmax 0.03125 in R3/R5/R8).

constexpr int DIMS     = 16;
constexpr int NODES    = 255;
constexpr int INTERNAL = 127;

__global__ __launch_bounds__(256) void polya_fused(
    const float* __restrict__ x,        // (n,16)
    const float* __restrict__ samples,  // (16,255)
    float* __restrict__ out,
    int n)
{
#pragma clang fp contract(off)
    __shared__ float s_split[DIMS * 128];   // 8 KB: splits, node j in [d*128+j]
    __shared__ float s_value[DIMS * 128];   // 8 KB: leaf values [d*128 + j-127]
    __shared__ float t_lo[2][1024];         // ping-pong frontier (level<=6)
    __shared__ float t_hi[2][1024];
    __shared__ float t_ac[2][1024];         // 24 KB temp; total 40 KB

    const int tid = threadIdx.x;
    if (tid < DIMS) {
        t_lo[0][tid << 6] = 0.0f;
        t_hi[0][tid << 6] = 1.0f;
        t_ac[0][tid << 6] = 0.0f;
    }
    __syncthreads();

    // ---- prologue: levels 0..6 as parents, one logf per parent ----
    for (int l = 0; l < 7; ++l) {
        const int jobs = DIMS << l;
        const int rp = l & 1, wp = rp ^ 1;
        for (int job = tid; job < jobs; job += 256) {
            const int d = job >> l;
            const int k = job & ((1 << l) - 1);
            const int i = (1 << l) - 1 + k;           // node id (level l)
            const int slot = (d << 6) + k;
            const float lo = t_lo[rp][slot];
            const float hi = t_hi[rp][slot];
            const float ac = t_ac[rp][slot];
            const float* s = samples + d * NODES;
            const float b = s[i];
            const float len = hi - lo;
            const float split = lo + b * len;          // EXACT mirror (no fma)
            s_split[(d << 7) + i] = split;
            const float ac2 = ac + logf(b);            // left-assoc chain order
            const float rhi = split + (1.0f - b) * len;
            if (l < 6) {
                const int cs = (d << 6) + 2 * k;       // children level l+1
                t_lo[wp][cs]     = lo;    t_hi[wp][cs]     = split; t_ac[wp][cs]     = ac2;
                t_lo[wp][cs + 1] = split; t_hi[wp][cs + 1] = rhi;   t_ac[wp][cs + 1] = ac2;
            } else {                                   // children are leaves
                const int jl = 2 * i + 1, jr = 2 * i + 2;   // 127..254
                const float vl = ac2 + logf(s[jl]) - logf(split - lo);
                const float vr = ac2 + logf(s[jr]) - logf(rhi - split);
                s_value[(d << 7) + (jl - INTERNAL)] = vl;
                s_value[(d << 7) + (jr - INTERNAL)] = vr;
            }
        }
        __syncthreads();
    }

    // ---- eval: R3 core, unchanged ----
    const int stride = gridDim.x * 256;
    for (int p = blockIdx.x * 256 + tid; p < n; p += stride) {
        const float4* xr = reinterpret_cast<const float4*>(x + (size_t)p * DIMS);
        float4 a = xr[0], b4 = xr[1], c4 = xr[2], e4 = xr[3];
        float xs[DIMS] = {a.x, a.y, a.z, a.w,  b4.x, b4.y, b4.z, b4.w,
                          c4.x, c4.y, c4.z, c4.w,  e4.x, e4.y, e4.z, e4.w};
        float acc = 0.0f;
#pragma unroll
        for (int d = 0; d < DIMS; ++d) {
            const float xv = xs[d];
            int idx = 0;
#pragma unroll
            for (int l = 0; l < 7; ++l) {
                float sp = s_split[(d << 7) + idx];
                idx = 2 * idx + 1 + (int)(xv > sp);    // x<=split -> left
            }
            acc += s_value[(d << 7) + (idx - INTERNAL)];
        }
        out[p] = acc * 0.0625f;   // mean over 16 dims (exact /16)
    }
}

extern "C" void kernel_launch(void* const* d_in, const int* in_sizes, int n_in,
                              void* d_out, int out_size, void* d_ws, size_t ws_size,
                              hipStream_t stream) {
    const float* x       = (const float*)d_in[0];   // (n,16) f32
    const float* samples = (const float*)d_in[1];   // (16,255) f32
    float* out = (float*)d_out;
    const int n = in_sizes[0] / DIMS;

    // 1024 blocks = 4 blocks/CU at 40 KB LDS -> ALL resident, prologue paid
    // once in parallel; grid-stride ~3.8 pts/thread.
    polya_fused<<<1024, 256, 0, stream>>>(x, samples, out, n);
}